// Round 6
// baseline (533.028 us; speedup 1.0000x reference)
//
#include <hip/hip_runtime.h>

// Problem constants (from reference setup_inputs):
//   x: (4,4096,1024) fp32 -> M=16384, dim=1024, hidden=4096, rank=16
//   w_fc: (4096,1024), w_proj: (1024,4096), u:(4096,16), v:(16,1024), fast_b:(16,16), gate scalar
// out: (16384,1024) fp32
//
// R1:  XOR-swizzled LDS -> conflicts 1.68e7 -> 0.
// R5:  BK=64 single-buffered 128^2 tile -> 179 us/gemm (~765 TF).
// R6:  256^2, 8 waves(128x64), 4-phase lockstep -> 157 us, MfmaUtil 38%.
// R7:  barrier-free reg pipeline               -> 151.5 us, MfmaUtil 37%.
// R10: m201-faithful 8-phase + counted vmcnt   -> 152 us, MfmaUtil 39%.
//   => three schedules converge: NOT schedule-bound. Arithmetic: 8 waves of
//      128x64 read 192 KB LDS per K-tile per CU (~2300 cyc @85 B/cyc) vs
//      2060 cyc MFMA/SIMD -> LDS-read traffic >= MFMA time. Ratio is
//      16384*(Wm+Wn)/(Wm*Wn) = 384 B/MFMA.
// R11: 4 waves of 128x128 (ratio 256 B/MFMA): LDS 128 KB/K-tile (~1000-1500
//      cyc) << MFMA 2060 cyc -> MFMA-bound. acc 256 VGPR + frags -> ~400
//      VGPR, 1 wave/SIMD (dedicated MFMA pipe, no contention). Dbuf LDS
//      128 KB, stage t+2 during t's compute, counted vmcnt(16) (vmcnt(0)
//      when nothing staged - R9 lesson). 2 barriers per K-tile only.

typedef unsigned short u16;
typedef __attribute__((ext_vector_type(8))) short short8;
typedef __attribute__((ext_vector_type(4))) float float4v;

#define M_TOK   16384
#define DIM     1024
#define HID     4096

// ---------- helpers ----------

__device__ __forceinline__ u16 f2bf(float f) {
    union { float f; unsigned u; } v; v.f = f;
    unsigned r = v.u + 0x7fffu + ((v.u >> 16) & 1u);   // RNE
    return (u16)(r >> 16);
}

__device__ __forceinline__ void gload_lds16(const u16* g, u16* l) {
    __builtin_amdgcn_global_load_lds(
        (const __attribute__((address_space(1))) void*)g,
        (__attribute__((address_space(3))) void*)l, 16, 0, 0);
}

// ---------- fused prologue kernel ----------
// blocks [0, HID)           : build W1 row b   (adapter T inlined)
// blocks [HID, HID+DIM)     : build W2 row b-HID
// blocks [HID+DIM, +16384)  : cvt x -> bf16

__global__ __launch_bounds__(256) void prologue_kernel(
    const float* __restrict__ x, const float* __restrict__ w_fc,
    const float* __restrict__ w_proj, const float* __restrict__ u,
    const float* __restrict__ fb, const float* __restrict__ v,
    const float* __restrict__ gate,
    u16* __restrict__ Xb, u16* __restrict__ W1, u16* __restrict__ W2) {
    const int b = blockIdx.x, tid = threadIdx.x;
    __shared__ float red[4];

    if (b < HID) {
        // ---- build_w1, row = b ----
        const int row = b;
        float s = 0.f;
#pragma unroll
        for (int jj = 0; jj < 4; jj++) s += fabsf(w_fc[row * 1024 + tid + jj * 256]);
#pragma unroll
        for (int o = 32; o > 0; o >>= 1) s += __shfl_down(s, o, 64);
        if ((tid & 63) == 0) red[tid >> 6] = s;
        __syncthreads();
        const float scale = fmaxf((red[0] + red[1] + red[2] + red[3]) * (1.f / 1024.f), 1e-5f);
        const float g = gate[0];
        float t[16];
#pragma unroll
        for (int r = 0; r < 16; r++) t[r] = 0.f;
#pragma unroll
        for (int k = 0; k < 16; k++) {
            const float uk = u[row * 16 + k];
#pragma unroll
            for (int r = 0; r < 16; r++) t[r] += uk * fb[k * 16 + r];
        }
#pragma unroll
        for (int jj = 0; jj < 4; jj++) {
            const int j = tid + jj * 256;
            const float wv = w_fc[row * 1024 + j];
            float tern = rintf(wv / scale);
            tern = fminf(1.f, fmaxf(-1.f, tern));
            float ad = 0.f;
#pragma unroll
            for (int r = 0; r < 16; r++) ad += t[r] * v[r * 1024 + j];
            W1[row * 1024 + j] = f2bf(tern * scale + g * ad);
        }
    } else if (b < HID + DIM) {
        // ---- build_w2, row = b - HID ----
        const int row = b - HID;
        float s = 0.f;
#pragma unroll
        for (int jj = 0; jj < 16; jj++) s += fabsf(w_proj[row * 4096 + tid + jj * 256]);
#pragma unroll
        for (int o = 32; o > 0; o >>= 1) s += __shfl_down(s, o, 64);
        if ((tid & 63) == 0) red[tid >> 6] = s;
        __syncthreads();
        const float scale = fmaxf((red[0] + red[1] + red[2] + red[3]) * (1.f / 4096.f), 1e-5f);
#pragma unroll
        for (int jj = 0; jj < 16; jj++) {
            const int j = tid + jj * 256;
            float tern = rintf(w_proj[row * 4096 + j] / scale);
            tern = fminf(1.f, fmaxf(-1.f, tern));
            W2[row * 4096 + j] = f2bf(tern * scale);
        }
    } else {
        // ---- cvt_x ----
        const int i = (b - (HID + DIM)) * 1024 + tid * 4;
        float4 vv = *reinterpret_cast<const float4*>(x + i);
        ushort4 o;
        o.x = f2bf(vv.x); o.y = f2bf(vv.y); o.z = f2bf(vv.z); o.w = f2bf(vv.w);
        *reinterpret_cast<ushort4*>(Xb + i) = o;
    }
}

// ---------- GEMM: C[M,N] = A[M,K] @ B[N,K]^T (both bf16 row-major) ----------
// 256x256 block, 4 waves (2M x 2N), per-wave 128x128 (acc 8x8 f32x4 = 256
// VGPR). BK=64, LDS dbuf 2x(A+B) = 128 KiB -> 1 block/CU, 1 wave/SIMD.
// Chunk q (of 2048/tile): row=q>>3, pos=q&7; pos p of row r holds k-chunk
// p^(r&7). With 256 threads: q = tid + 256c -> row = (tid>>3)+32c,
// kc = (tid&7)^((tid>>3)&7)  (CONSTANT across c) -> staging addressing is
// 2 base pointers + compile-time offsets.
//
// Per K-tile: {32 ds_read_b128 -> 128 MFMA (compiler-counted lgkm waits
// interleave them)} then handshake: BAR (all reads of buf[cur] consumed by
// MFMA data-deps) | STAGE(buf[cur] <- t+2, 16 gloads) | vmcnt(16) (drains
// t+1's 16, keeps t+2's in flight; vmcnt(0) when nothing staged [R9 rule])
// | BAR (buf[nxt] valid). DMA for tile t+1 was issued one full compute
// (~2600 cyc) before its wait -> never exposed.
// LDS balance per K-tile per CU: reads 4x32 KB = 128 KB (~1000-1500 cyc)
// + stage-writes 64 KB vs MFMA 128x16.1 = 2060 cyc/SIMD -> MFMA-bound.
template <int N, int K, int EPI>
__global__ __launch_bounds__(256, 1) void gemm_w4(const u16* __restrict__ A,
                                                  const u16* __restrict__ B,
                                                  void* __restrict__ Cv) {
    constexpr int GM  = M_TOK / 256;   // 64
    constexpr int GN  = N / 256;
    constexpr int NWG = GM * GN;       // %8==0
    constexpr int NT  = K / 64;        // 16 / 64

    __shared__ alignas(16) u16 lds[2][2][256 * 64];   // 128 KiB

    const int tid  = threadIdx.x;
    const int wave = tid >> 6, lane = tid & 63;
    const int lr = lane & 15, quad = lane >> 4;
    const int wm = (wave >> 1) << 7;   // 0 / 128
    const int wn = (wave & 1) << 7;    // 0 / 128

    // T1 chunked-bijective XCD swizzle (NWG % 8 == 0)
    int flat = (int)blockIdx.x;
    flat = (flat & 7) * (NWG / 8) + (flat >> 3);
    const int bm = flat % GM;
    const int bn = flat / GM;

    // staging: chunk c (0..7) of this thread: row = r0 + 32c, k-chunk kc
    // (constant), LDS u16-offset tid*8 + 2048c. Wave-linear LDS dest
    // (base + lane*16B) -> gload_lds-compatible (m104).
    const int r0 = tid >> 3;                       // 0..31
    const int kc = (tid & 7) ^ (r0 & 7);
    const u16* Ag0 = A + (size_t)(bm * 256 + r0) * K + kc * 8;
    const u16* Bg0 = B + (size_t)(bn * 256 + r0) * K + kc * 8;

    float4v acc[8][8];
#pragma unroll
    for (int i = 0; i < 8; i++)
#pragma unroll
        for (int j = 0; j < 8; j++) acc[i][j] = (float4v)0.0f;

    // fragment addressing: elem off = (wrow+lr+16*i)*64 + pk[ks]
    const int pk0 = (quad ^ (lr & 7)) * 8;          // k-step 0 chunk pos
    const int pk1 = ((4 + quad) ^ (lr & 7)) * 8;    // k-step 1 chunk pos
    const int aoff = (wm + lr) * 64;
    const int boff = (wn + lr) * 64;

#define CFENCE() asm volatile("" ::: "memory")
#define BARX()   do { CFENCE(); __builtin_amdgcn_s_barrier(); CFENCE(); } while (0)
#define WVM16()  asm volatile("s_waitcnt vmcnt(16)" ::: "memory")
#define WVM0()   asm volatile("s_waitcnt vmcnt(0)" ::: "memory")

#define STAGE(buf, k0)                                                        \
    do {                                                                      \
        _Pragma("unroll")                                                     \
        for (int c_ = 0; c_ < 8; c_++)                                        \
            gload_lds16(Ag0 + (size_t)c_ * 32 * K + (k0),                     \
                        &lds[buf][0][0] + tid * 8 + c_ * 2048);               \
        _Pragma("unroll")                                                     \
        for (int c_ = 0; c_ < 8; c_++)                                        \
            gload_lds16(Bg0 + (size_t)c_ * 32 * K + (k0),                     \
                        &lds[buf][1][0] + tid * 8 + c_ * 2048);               \
    } while (0)

    // ---- staging prologue: tile0 -> buf0, tile1 -> buf1 ----
    STAGE(0, 0);
    STAGE(1, 64);
    WVM16();                 // tile0's 16 retired (FIFO); tile1 in flight
    BARX();

#pragma unroll 1
    for (int t = 0; t < NT; ++t) {
        const int cur = t & 1;
        const u16* Ab = &lds[cur][0][0];
        const u16* Bb = &lds[cur][1][0];

        short8 Af[8][2], Bf[8][2];
#pragma unroll
        for (int i = 0; i < 8; i++) {
            Af[i][0] = *reinterpret_cast<const short8*>(Ab + aoff + 1024 * i + pk0);
            Af[i][1] = *reinterpret_cast<const short8*>(Ab + aoff + 1024 * i + pk1);
        }
#pragma unroll
        for (int j = 0; j < 8; j++) {
            Bf[j][0] = *reinterpret_cast<const short8*>(Bb + boff + 1024 * j + pk0);
            Bf[j][1] = *reinterpret_cast<const short8*>(Bb + boff + 1024 * j + pk1);
        }

        // 128 MFMA; compiler inserts counted lgkm waits so early MFMAs run
        // while later ds_reads are still in flight. Per-acc K-order (ks0
        // then ks1, tiles in order) identical to all previous rounds.
#pragma unroll
        for (int ks = 0; ks < 2; ks++)
#pragma unroll
            for (int i = 0; i < 8; i++)
#pragma unroll
                for (int j = 0; j < 8; j++)
                    acc[i][j] = __builtin_amdgcn_mfma_f32_16x16x32_bf16(
                        Af[i][ks], Bf[j][ks], acc[i][j], 0, 0, 0);

        // ---- per-tile handshake ----
        if (t + 1 < NT) {
            BARX();                    // all waves' reads of buf[cur] retired
            if (t + 2 < NT) {
                STAGE(cur, (t + 2) * 64);
                WVM16();               // drain t+1's 16, keep t+2's in flight
            } else {
                WVM0();                // nothing staged: must drain t+1 fully
            }
            BARX();                    // buf[nxt] valid for all waves
        }
    }
    WVM0();   // drain any remaining staging DMA before epilogue

#undef CFENCE
#undef BARX
#undef WVM16
#undef WVM0
#undef STAGE

    // ---- epilogue. C/D layout: col=lane&15, row=quad*4+reg (m89/m91-verified) ----
    const int row0 = bm * 256 + wm + quad * 4;
    const int col0 = bn * 256 + wn + lr;
#pragma unroll
    for (int i = 0; i < 8; i++)
#pragma unroll
        for (int j = 0; j < 8; j++) {
            const int col = col0 + j * 16;
            const float4v a = acc[i][j];
#pragma unroll
            for (int r = 0; r < 4; r++) {
                const int row = row0 + i * 16 + r;
                if (EPI == 0) {
                    const float rr = fmaxf(a[r], 0.f);
                    ((u16*)Cv)[(size_t)row * N + col] = f2bf(rr * rr);
                } else {
                    ((float*)Cv)[(size_t)row * N + col] = a[r];
                }
            }
        }
}

// ---------- launch ----------

extern "C" void kernel_launch(void* const* d_in, const int* in_sizes, int n_in,
                              void* d_out, int out_size, void* d_ws, size_t ws_size,
                              hipStream_t stream) {
    const float* x      = (const float*)d_in[0];
    const float* fast_b = (const float*)d_in[1];
    const float* w_fc   = (const float*)d_in[2];
    const float* w_proj = (const float*)d_in[3];
    const float* u      = (const float*)d_in[4];
    const float* v      = (const float*)d_in[5];
    const float* gate   = (const float*)d_in[6];
    float* out = (float*)d_out;

    char* ws = (char*)d_ws;
    u16*   Xb  = (u16*)(ws + 0);                         // 16384*1024*2 = 32 MB
    u16*   W1  = (u16*)(ws + 33554432);                  // 4096*1024*2  =  8 MB
    u16*   W2  = (u16*)(ws + 41943040);                  // 1024*4096*2  =  8 MB
    u16*   RSQ = (u16*)(ws + 50331648);                  // 16384*4096*2 = 128 MB

    // fused prologue: W1 rows | W2 rows | x conversion
    prologue_kernel<<<HID + DIM + M_TOK * DIM / (256 * 4), 256, 0, stream>>>(
        x, w_fc, w_proj, u, fast_b, v, gate, Xb, W1, W2);

    // GEMM1: (16384,1024) @ (4096,1024)^T -> relu^2 bf16 (16384,4096); 1024 wgs
    gemm_w4<HID, DIM, 0><<<dim3((M_TOK / 256) * (HID / 256)), 256, 0, stream>>>(Xb, W1, RSQ);
    // GEMM2: (16384,4096) @ (1024,4096)^T -> fp32 out (16384,1024); 256 wgs
    gemm_w4<DIM, HID, 1><<<dim3((M_TOK / 256) * (DIM / 256)), 256, 0, stream>>>(RSQ, W2, out);
}